// Round 3
// baseline (177.936 us; speedup 1.0000x reference)
//
#include <hip/hip_runtime.h>

// FeaturePropagationV2: 3-NN inverse-distance interpolation + Linear, fused as:
//   G = feature2 @ W.T          (precomputed once, 8192x256)
//   out[i] = sum_k w_k * G[idx_k] + b
//
// kNN: fast f32 scan (m = 0.5|x|^2 - q.x, ranking-equivalent) nominates top-4
// candidates; finalists are re-ranked with a bit-level replication of the
// reference's f32 formula d2 = q_sq + x2_sq - 2*(q@xyz2.T) (numpy/BLAS
// rounding: fma k-chain dot, plain-add norms, no contraction), stable
// (d2, idx) order matching lax.top_k.

#define FLT_BIG 3.402823466e+38f

__global__ __launch_bounds__(256) void prep_kernel(const float* __restrict__ xyz2,
                                                   float4* __restrict__ pack, int N2) {
    int j = blockIdx.x * 256 + threadIdx.x;
    if (j < N2) {
        float x = xyz2[3 * j + 0];
        float y = xyz2[3 * j + 1];
        float z = xyz2[3 * j + 2];
        float4 p;
        p.x = x; p.y = y; p.z = z;
        p.w = 0.5f * (x * x + y * y + z * z);   // scan metric only (rounding-free zone)
        pack[j] = p;
    }
}

// C[m][n] = sum_k A[m][k] * B[n][k]
__global__ __launch_bounds__(256) void gemm_nt_f32(const float* __restrict__ A,
                                                   const float* __restrict__ B,
                                                   float* __restrict__ C,
                                                   int M, int N, int K) {
    __shared__ float As[64][68];
    __shared__ float Bs[64][68];

    const int t  = threadIdx.x;
    const int tx = t & 15;
    const int ty = t >> 4;
    const int bm = blockIdx.x * 64;
    const int bn = blockIdx.y * 64;

    float acc[4][4] = {{0.f}};

    for (int kt = 0; kt < K; kt += 64) {
#pragma unroll
        for (int rr = 0; rr < 4; ++rr) {
            int r = ty + 16 * rr;
            int c = tx * 4;
            float4 av = *(const float4*)(A + (size_t)(bm + r) * K + kt + c);
            As[c + 0][r] = av.x;
            As[c + 1][r] = av.y;
            As[c + 2][r] = av.z;
            As[c + 3][r] = av.w;
            float4 bv = *(const float4*)(B + (size_t)(bn + r) * K + kt + c);
            Bs[c + 0][r] = bv.x;
            Bs[c + 1][r] = bv.y;
            Bs[c + 2][r] = bv.z;
            Bs[c + 3][r] = bv.w;
        }
        __syncthreads();

#pragma unroll 8
        for (int k = 0; k < 64; ++k) {
            float4 a4 = *(const float4*)&As[k][ty * 4];
            float4 b4 = *(const float4*)&Bs[k][tx * 4];
            float a[4] = {a4.x, a4.y, a4.z, a4.w};
            float b[4] = {b4.x, b4.y, b4.z, b4.w};
#pragma unroll
            for (int i = 0; i < 4; ++i)
#pragma unroll
                for (int j = 0; j < 4; ++j)
                    acc[i][j] = fmaf(a[i], b[j], acc[i][j]);
        }
        __syncthreads();
    }

#pragma unroll
    for (int i = 0; i < 4; ++i) {
        float4 v;
        v.x = acc[i][0]; v.y = acc[i][1]; v.z = acc[i][2]; v.w = acc[i][3];
        *(float4*)(C + (size_t)(bm + ty * 4 + i) * N + bn + tx * 4) = v;
    }
}

// keep 4 smallest (sorted b0<=b1<=b2<=b3); strict < keeps earlier index on ties
#define TOP4_INSERT(mv, ji)                                              \
    do {                                                                 \
        if ((mv) < b3) {                                                 \
            if ((mv) < b1) {                                             \
                b3 = b2; i3 = i2;                                        \
                b2 = b1; i2 = i1;                                        \
                if ((mv) < b0) { b1 = b0; i1 = i0; b0 = (mv); i0 = (ji); } \
                else            { b1 = (mv); i1 = (ji); }                \
            } else {                                                     \
                if ((mv) < b2) { b3 = b2; i3 = i2; b2 = (mv); i2 = (ji); } \
                else            { b3 = (mv); i3 = (ji); }                \
            }                                                            \
        }                                                                \
    } while (0)

// Block: 512 threads = 8 waves, owns 64 fine points (lane <-> fine point).
// Wave w scans coarse slab [w*1024,(w+1)*1024) keeping per-lane top-4 of the
// fast metric m. Wave 0 merges 8x4 candidates, re-ranks the final 4 with the
// exact reference-f32 formula, computes f32 weights, then all 8 waves gather
// G rows and write out.
__global__ __launch_bounds__(512) void knn_gather(const float* __restrict__ xyz1,
                                                  const float4* __restrict__ pack,
                                                  const float4* __restrict__ G4,    // [N2*64]
                                                  const float4* __restrict__ bias4, // [64]
                                                  float4* __restrict__ out4,        // [N1*64]
                                                  int N2) {
    __shared__ float md[8][64][4];
    __shared__ int   mi[8][64][4];
    __shared__ float swgt[64][3];
    __shared__ int   sidx[64][3];

    const int tid  = threadIdx.x;
    const int wave = __builtin_amdgcn_readfirstlane(tid >> 6);
    const int lane = tid & 63;
    const int fine = blockIdx.x * 64 + lane;

    const float qx = xyz1[3 * fine + 0];
    const float qy = xyz1[3 * fine + 1];
    const float qz = xyz1[3 * fine + 2];
    const float nqx = -qx, nqy = -qy, nqz = -qz;

    float b0 = FLT_BIG, b1 = FLT_BIG, b2 = FLT_BIG, b3 = FLT_BIG;
    int   i0 = 0,       i1 = 0,       i2 = 0,       i3 = 0;

    const int chunk = N2 >> 3;                 // 1024
    const int base  = wave * chunk;            // wave-uniform (SGPR)
#pragma unroll 4
    for (int jj = 0; jj < chunk; ++jj) {
        int j = base + jj;                     // uniform -> scalar load
        float4 p = pack[j];
        // fast ranking metric: 0.5|x|^2 - q.x  (3 FMA); only nominates candidates
        float m = fmaf(nqx, p.x, fmaf(nqy, p.y, fmaf(nqz, p.z, p.w)));
        TOP4_INSERT(m, j);
    }

    md[wave][lane][0] = b0; mi[wave][lane][0] = i0;
    md[wave][lane][1] = b1; mi[wave][lane][1] = i1;
    md[wave][lane][2] = b2; mi[wave][lane][2] = i2;
    md[wave][lane][3] = b3; mi[wave][lane][3] = i3;
    __syncthreads();

    if (tid < 64) {
        // wave 0's registers already hold slab-0 top4; merge slabs 1..7
#pragma unroll
        for (int w = 1; w < 8; ++w) {
#pragma unroll
            for (int k = 0; k < 4; ++k) {
                float m = md[w][tid][k];
                int   j = mi[w][tid][k];
                TOP4_INSERT(m, j);
            }
        }
        // ---- exact replication of the reference f32 distance ----
        // q_sq = (qx*qx + qy*qy) + qz*qz   (plain mul/add, no contraction)
        float qsq = __fadd_rn(__fadd_rn(__fmul_rn(qx, qx), __fmul_rn(qy, qy)),
                              __fmul_rn(qz, qz));
        int   idx[4] = {i0, i1, i2, i3};
        float dd[4];
#pragma unroll
        for (int k = 0; k < 4; ++k) {
            float4 p = pack[idx[k]];
            // x2_sq = (x*x + y*y) + z*z
            float x2s = __fadd_rn(__fadd_rn(__fmul_rn(p.x, p.x), __fmul_rn(p.y, p.y)),
                                  __fmul_rn(p.z, p.z));
            // dot = fma(qz,z, fma(qy,y, rn(qx*x)))  — BLAS k-ascending fma chain
            float dot = __fmaf_rn(qz, p.z, __fmaf_rn(qy, p.y, __fmul_rn(qx, p.x)));
            // d2 = (q_sq + x2_sq) - 2*dot
            dd[k] = __fsub_rn(__fadd_rn(qsq, x2s), __fmul_rn(2.0f, dot));
        }
        // stable selection of 3 smallest by (d2, idx) — matches lax.top_k order
        int ord[4] = {0, 1, 2, 3};
#pragma unroll
        for (int a = 0; a < 3; ++a) {
            int best = a;
#pragma unroll
            for (int c = a + 1; c < 4; ++c) {
                bool lt = (dd[ord[c]] < dd[ord[best]]) ||
                          (dd[ord[c]] == dd[ord[best]] && idx[ord[c]] < idx[ord[best]]);
                if (lt) best = c;
            }
            int tmp = ord[a]; ord[a] = ord[best]; ord[best] = tmp;
        }
        // f32 inverse-distance weights, reference op order
        float w0 = 1.0f / (__fadd_rn(sqrtf(fmaxf(dd[ord[0]], 1e-12f)), 1e-8f));
        float w1 = 1.0f / (__fadd_rn(sqrtf(fmaxf(dd[ord[1]], 1e-12f)), 1e-8f));
        float w2 = 1.0f / (__fadd_rn(sqrtf(fmaxf(dd[ord[2]], 1e-12f)), 1e-8f));
        float wsum = __fadd_rn(__fadd_rn(w0, w1), w2);
        swgt[tid][0] = w0 / wsum; sidx[tid][0] = idx[ord[0]];
        swgt[tid][1] = w1 / wsum; sidx[tid][1] = idx[ord[1]];
        swgt[tid][2] = w2 / wsum; sidx[tid][2] = idx[ord[2]];
    }
    __syncthreads();

    const float4 bb = bias4[lane];
#pragma unroll
    for (int p = 0; p < 8; ++p) {
        int fl = wave * 8 + p;
        float w0 = swgt[fl][0];
        float w1 = swgt[fl][1];
        float w2 = swgt[fl][2];
        int j0 = sidx[fl][0];
        int j1 = sidx[fl][1];
        int j2 = sidx[fl][2];
        float4 g0 = G4[(size_t)j0 * 64 + lane];
        float4 g1 = G4[(size_t)j1 * 64 + lane];
        float4 g2 = G4[(size_t)j2 * 64 + lane];
        float4 o;
        o.x = fmaf(w0, g0.x, fmaf(w1, g1.x, fmaf(w2, g2.x, bb.x)));
        o.y = fmaf(w0, g0.y, fmaf(w1, g1.y, fmaf(w2, g2.y, bb.y)));
        o.z = fmaf(w0, g0.z, fmaf(w1, g1.z, fmaf(w2, g2.z, bb.z)));
        o.w = fmaf(w0, g0.w, fmaf(w1, g1.w, fmaf(w2, g2.w, bb.w)));
        out4[(size_t)(blockIdx.x * 64 + fl) * 64 + lane] = o;
    }
}

extern "C" void kernel_launch(void* const* d_in, const int* in_sizes, int n_in,
                              void* d_out, int out_size, void* d_ws, size_t ws_size,
                              hipStream_t stream) {
    const float* xyz1 = (const float*)d_in[0];
    const float* xyz2 = (const float*)d_in[1];
    // d_in[2] = feature1 (unused by the reference computation)
    const float* f2   = (const float*)d_in[3];
    const float* W    = (const float*)d_in[6];
    const float* bias = (const float*)d_in[7];

    const int N1  = in_sizes[0] / 3;   // 32768
    const int N2  = in_sizes[1] / 3;   // 8192
    const int C   = in_sizes[3] / N2;  // 256
    const int OUT = in_sizes[7];       // 256

    float*  G    = (float*)d_ws;                                   // N2*OUT f32 = 8 MB
    float4* pack = (float4*)((char*)d_ws + (size_t)N2 * OUT * 4);  // N2 float4 = 128 KB

    prep_kernel<<<(N2 + 255) / 256, 256, 0, stream>>>(xyz2, pack, N2);

    dim3 ggrid(N2 / 64, OUT / 64);
    gemm_nt_f32<<<ggrid, 256, 0, stream>>>(f2, W, G, N2, OUT, C);

    knn_gather<<<N1 / 64, 512, 0, stream>>>(xyz1, pack, (const float4*)G,
                                            (const float4*)bias, (float4*)d_out, N2);
}

// Round 4
// 159.362 us; speedup vs baseline: 1.1166x; 1.1166x over previous
//
#include <hip/hip_runtime.h>

// FeaturePropagationV2: 3-NN inverse-distance interpolation + Linear, fused as:
//   G = feature2 @ W.T          (precomputed once, 8192x256)
//   out[i] = sum_k w_k * G[idx_k] + b
//
// kNN via two-phase threshold filter:
//   Phase 1: sample (first 1/4 of each slab), branchless value-only sloppy
//            top-4 -> per-query threshold t (4th-smallest + margin; sloppiness
//            only inflates t = safe).
//   Phase 2: full scan, 3 FMA + 1 cmp per point; survivors (m <= t) appended
//            to per-(wave,query) LDS rings (single writer, no atomics).
//   Select : exact reference-f32 re-score of all survivors, stable (d2,idx)
//            top-3 (matches lax.top_k), reference-order f32 weights.

#define FLT_BIG 3.402823466e+38f
#define CAP     24
#define MARGIN  3e-5f

__global__ __launch_bounds__(256) void prep_kernel(const float* __restrict__ xyz2,
                                                   float4* __restrict__ pack, int N2) {
    int j = blockIdx.x * 256 + threadIdx.x;
    if (j < N2) {
        float x = xyz2[3 * j + 0];
        float y = xyz2[3 * j + 1];
        float z = xyz2[3 * j + 2];
        float4 p;
        p.x = x; p.y = y; p.z = z;
        p.w = 0.5f * (x * x + y * y + z * z);   // scan metric only
        pack[j] = p;
    }
}

// C[m][n] = sum_k A[m][k] * B[n][k]   (unchanged from passing round)
__global__ __launch_bounds__(256) void gemm_nt_f32(const float* __restrict__ A,
                                                   const float* __restrict__ B,
                                                   float* __restrict__ C,
                                                   int M, int N, int K) {
    __shared__ float As[64][68];
    __shared__ float Bs[64][68];

    const int t  = threadIdx.x;
    const int tx = t & 15;
    const int ty = t >> 4;
    const int bm = blockIdx.x * 64;
    const int bn = blockIdx.y * 64;

    float acc[4][4] = {{0.f}};

    for (int kt = 0; kt < K; kt += 64) {
#pragma unroll
        for (int rr = 0; rr < 4; ++rr) {
            int r = ty + 16 * rr;
            int c = tx * 4;
            float4 av = *(const float4*)(A + (size_t)(bm + r) * K + kt + c);
            As[c + 0][r] = av.x;
            As[c + 1][r] = av.y;
            As[c + 2][r] = av.z;
            As[c + 3][r] = av.w;
            float4 bv = *(const float4*)(B + (size_t)(bn + r) * K + kt + c);
            Bs[c + 0][r] = bv.x;
            Bs[c + 1][r] = bv.y;
            Bs[c + 2][r] = bv.z;
            Bs[c + 3][r] = bv.w;
        }
        __syncthreads();

#pragma unroll 8
        for (int k = 0; k < 64; ++k) {
            float4 a4 = *(const float4*)&As[k][ty * 4];
            float4 b4 = *(const float4*)&Bs[k][tx * 4];
            float a[4] = {a4.x, a4.y, a4.z, a4.w};
            float b[4] = {b4.x, b4.y, b4.z, b4.w};
#pragma unroll
            for (int i = 0; i < 4; ++i)
#pragma unroll
                for (int j = 0; j < 4; ++j)
                    acc[i][j] = fmaf(a[i], b[j], acc[i][j]);
        }
        __syncthreads();
    }

#pragma unroll
    for (int i = 0; i < 4; ++i) {
        float4 v;
        v.x = acc[i][0]; v.y = acc[i][1]; v.z = acc[i][2]; v.w = acc[i][3];
        *(float4*)(C + (size_t)(bm + ty * 4 + i) * N + bn + tx * 4) = v;
    }
}

// branchless value-only sorted top-4 insert: 7 min/max ops
#define TOP4V_INSERT(mv)                                           \
    do {                                                           \
        float _x  = (mv);                                          \
        float _n0 = fminf(b0, _x);  float _y0 = fmaxf(b0, _x); b0 = _n0; \
        float _n1 = fminf(b1, _y0); float _y1 = fmaxf(b1, _y0); b1 = _n1; \
        float _n2 = fminf(b2, _y1); float _y2 = fmaxf(b2, _y1); b2 = _n2; \
        b3 = fminf(b3, _y2);                                       \
    } while (0)

// Block: 512 threads = 8 waves, owns 64 fine points (lane <-> query).
// Wave w scans coarse slab [w*1024,(w+1)*1024).
__global__ __launch_bounds__(512) void knn_gather(const float* __restrict__ xyz1,
                                                  const float4* __restrict__ pack,
                                                  const float4* __restrict__ G4,    // [N2*64]
                                                  const float4* __restrict__ bias4, // [64]
                                                  float4* __restrict__ out4,        // [N1*64]
                                                  int N2) {
    __shared__ float          md[8][64][4];
    __shared__ float          thr[64];
    __shared__ unsigned short ring[8][64][CAP];
    __shared__ unsigned short cnts[8][64];
    __shared__ float          swgt[64][3];
    __shared__ int            sidx[64][3];

    const int tid  = threadIdx.x;
    const int wave = __builtin_amdgcn_readfirstlane(tid >> 6);
    const int lane = tid & 63;
    const int fine = blockIdx.x * 64 + lane;

    const float qx = xyz1[3 * fine + 0];
    const float qy = xyz1[3 * fine + 1];
    const float qz = xyz1[3 * fine + 2];
    const float nqx = -qx, nqy = -qy, nqz = -qz;

    const int chunk = N2 >> 3;                 // 1024
    const int base  = wave * chunk;            // wave-uniform (SGPR)

    // ---- Phase 1: sampled sloppy top-4 (values only) -> threshold ----
    {
        float b0 = FLT_BIG, b1 = FLT_BIG, b2 = FLT_BIG, b3 = FLT_BIG;
        const int ns = chunk >> 2;             // first 256 of slab (iid data)
#pragma unroll 2
        for (int jj = 0; jj < ns; jj += 4) {
            int j = base + jj;
            float4 p0 = pack[j + 0];
            float4 p1 = pack[j + 1];
            float4 p2 = pack[j + 2];
            float4 p3 = pack[j + 3];
            float m0 = fmaf(nqx, p0.x, fmaf(nqy, p0.y, fmaf(nqz, p0.z, p0.w)));
            float m1 = fmaf(nqx, p1.x, fmaf(nqy, p1.y, fmaf(nqz, p1.z, p1.w)));
            float m2 = fmaf(nqx, p2.x, fmaf(nqy, p2.y, fmaf(nqz, p2.z, p2.w)));
            float m3 = fmaf(nqx, p3.x, fmaf(nqy, p3.y, fmaf(nqz, p3.z, p3.w)));
            float mm = fminf(fminf(m0, m1), fminf(m2, m3));   // batch-min only:
            TOP4V_INSERT(mm);                                  // under-maintains ->
        }                                                      // larger t (safe)
        md[wave][lane][0] = b0;
        md[wave][lane][1] = b1;
        md[wave][lane][2] = b2;
        md[wave][lane][3] = b3;
    }
    __syncthreads();

    if (tid < 64) {
        float b0 = FLT_BIG, b1 = FLT_BIG, b2 = FLT_BIG, b3 = FLT_BIG;
#pragma unroll
        for (int w = 0; w < 8; ++w)
#pragma unroll
            for (int k = 0; k < 4; ++k)
                TOP4V_INSERT(md[w][tid][k]);
        thr[tid] = b3 + MARGIN;   // >= sample-4th >= true-4th; margin covers
    }                              // formula-rounding differences vs ref d2
    __syncthreads();

    // ---- Phase 2: full scan, threshold filter -> survivor rings ----
    {
        const float t = thr[lane];
        int cnt = 0;
        unsigned short* myring = ring[wave][lane];
#pragma unroll 2
        for (int jj = 0; jj < chunk; jj += 4) {
            int j = base + jj;
            float4 p0 = pack[j + 0];
            float4 p1 = pack[j + 1];
            float4 p2 = pack[j + 2];
            float4 p3 = pack[j + 3];
            float m0 = fmaf(nqx, p0.x, fmaf(nqy, p0.y, fmaf(nqz, p0.z, p0.w)));
            float m1 = fmaf(nqx, p1.x, fmaf(nqy, p1.y, fmaf(nqz, p1.z, p1.w)));
            float m2 = fmaf(nqx, p2.x, fmaf(nqy, p2.y, fmaf(nqz, p2.z, p2.w)));
            float m3 = fmaf(nqx, p3.x, fmaf(nqy, p3.y, fmaf(nqz, p3.z, p3.w)));
            bool room = cnt < (CAP - 4);
            bool a0 = (m0 <= t) & room;
            bool a1 = (m1 <= t) & room;
            bool a2 = (m2 <= t) & room;
            bool a3 = (m3 <= t) & room;
            if (a0 | a1 | a2 | a3) {           // rare-ish wave-any branch
                if (a0) { myring[cnt] = (unsigned short)(j + 0); ++cnt; }
                if (a1) { myring[cnt] = (unsigned short)(j + 1); ++cnt; }
                if (a2) { myring[cnt] = (unsigned short)(j + 2); ++cnt; }
                if (a3) { myring[cnt] = (unsigned short)(j + 3); ++cnt; }
            }
        }
        cnts[wave][lane] = (unsigned short)cnt;
    }
    __syncthreads();

    // ---- Selection: exact ref-f32 re-score of survivors, stable top-3 ----
    if ((tid & 7) == 0) {
        const int q  = tid >> 3;
        const int fq = blockIdx.x * 64 + q;
        const float sqx = xyz1[3 * fq + 0];
        const float sqy = xyz1[3 * fq + 1];
        const float sqz = xyz1[3 * fq + 2];
        // q_sq = (qx*qx + qy*qy) + qz*qz  (no contraction, ref rounding)
        const float qsq = __fadd_rn(__fadd_rn(__fmul_rn(sqx, sqx), __fmul_rn(sqy, sqy)),
                                    __fmul_rn(sqz, sqz));
        float d0 = FLT_BIG, d1 = FLT_BIG, d2v = FLT_BIG;
        int   j0 = 0x7fffffff, j1 = 0x7fffffff, j2 = 0x7fffffff;

        for (int w = 0; w < 8; ++w) {
            const int n = cnts[w][q];
            for (int e = 0; e < n; ++e) {
                const int j = ring[w][q][e];
                float4 p = pack[j];
                // x2_sq = (x*x + y*y) + z*z
                float x2s = __fadd_rn(__fadd_rn(__fmul_rn(p.x, p.x), __fmul_rn(p.y, p.y)),
                                      __fmul_rn(p.z, p.z));
                // dot = fma(qz,z, fma(qy,y, rn(qx*x)))  — BLAS k-ascending chain
                float dot = __fmaf_rn(sqz, p.z, __fmaf_rn(sqy, p.y, __fmul_rn(sqx, p.x)));
                // d2 = (q_sq + x2_sq) - 2*dot
                float dd = __fsub_rn(__fadd_rn(qsq, x2s), __fmul_rn(2.0f, dot));
                // stable (d2, idx) insert into sorted top-3
                bool lt2 = (dd < d2v) || (dd == d2v && j < j2);
                if (lt2) {
                    bool lt1 = (dd < d1) || (dd == d1 && j < j1);
                    if (lt1) {
                        d2v = d1; j2 = j1;
                        bool lt0 = (dd < d0) || (dd == d0 && j < j0);
                        if (lt0) { d1 = d0; j1 = j0; d0 = dd; j0 = j; }
                        else     { d1 = dd; j1 = j; }
                    } else { d2v = dd; j2 = j; }
                }
            }
        }
        // f32 inverse-distance weights, reference op order
        float w0 = 1.0f / (__fadd_rn(sqrtf(fmaxf(d0,  1e-12f)), 1e-8f));
        float w1 = 1.0f / (__fadd_rn(sqrtf(fmaxf(d1,  1e-12f)), 1e-8f));
        float w2 = 1.0f / (__fadd_rn(sqrtf(fmaxf(d2v, 1e-12f)), 1e-8f));
        float wsum = __fadd_rn(__fadd_rn(w0, w1), w2);
        swgt[q][0] = w0 / wsum; sidx[q][0] = j0;
        swgt[q][1] = w1 / wsum; sidx[q][1] = j1;
        swgt[q][2] = w2 / wsum; sidx[q][2] = j2;
    }
    __syncthreads();

    // ---- Gather: out[fine] = w0*G[j0] + w1*G[j1] + w2*G[j2] + b ----
    const float4 bb = bias4[lane];
#pragma unroll
    for (int p = 0; p < 8; ++p) {
        int fl = wave * 8 + p;
        float w0 = swgt[fl][0];
        float w1 = swgt[fl][1];
        float w2 = swgt[fl][2];
        int j0 = sidx[fl][0];
        int j1 = sidx[fl][1];
        int j2 = sidx[fl][2];
        float4 g0 = G4[(size_t)j0 * 64 + lane];
        float4 g1 = G4[(size_t)j1 * 64 + lane];
        float4 g2 = G4[(size_t)j2 * 64 + lane];
        float4 o;
        o.x = fmaf(w0, g0.x, fmaf(w1, g1.x, fmaf(w2, g2.x, bb.x)));
        o.y = fmaf(w0, g0.y, fmaf(w1, g1.y, fmaf(w2, g2.y, bb.y)));
        o.z = fmaf(w0, g0.z, fmaf(w1, g1.z, fmaf(w2, g2.z, bb.z)));
        o.w = fmaf(w0, g0.w, fmaf(w1, g1.w, fmaf(w2, g2.w, bb.w)));
        out4[(size_t)(blockIdx.x * 64 + fl) * 64 + lane] = o;
    }
}

extern "C" void kernel_launch(void* const* d_in, const int* in_sizes, int n_in,
                              void* d_out, int out_size, void* d_ws, size_t ws_size,
                              hipStream_t stream) {
    const float* xyz1 = (const float*)d_in[0];
    const float* xyz2 = (const float*)d_in[1];
    // d_in[2] = feature1 (unused by the reference computation)
    const float* f2   = (const float*)d_in[3];
    const float* W    = (const float*)d_in[6];
    const float* bias = (const float*)d_in[7];

    const int N1  = in_sizes[0] / 3;   // 32768
    const int N2  = in_sizes[1] / 3;   // 8192
    const int C   = in_sizes[3] / N2;  // 256
    const int OUT = in_sizes[7];       // 256

    float*  G    = (float*)d_ws;                                   // N2*OUT f32 = 8 MB
    float4* pack = (float4*)((char*)d_ws + (size_t)N2 * OUT * 4);  // N2 float4 = 128 KB

    prep_kernel<<<(N2 + 255) / 256, 256, 0, stream>>>(xyz2, pack, N2);

    dim3 ggrid(N2 / 64, OUT / 64);
    gemm_nt_f32<<<ggrid, 256, 0, stream>>>(f2, W, G, N2, OUT, C);

    knn_gather<<<N1 / 64, 512, 0, stream>>>(xyz1, pack, (const float4*)G,
                                            (const float4*)bias, (float4*)d_out, N2);
}